// Round 18
// baseline (355.892 us; speedup 1.0000x reference)
//
#include <hip/hip_runtime.h>
#include <hip/hip_bf16.h>

#define N_NODES 50000
#define N_EDGES 800000
#define N_GRAPHS 64
#define IN_DIM 128
#define HID_DIM 256
#define M_PAD 50048   // N_NODES padded to multiple of 64 for GEMM staging

typedef short sh8 __attribute__((ext_vector_type(8)));
typedef float f4 __attribute__((ext_vector_type(4)));
typedef float f2 __attribute__((ext_vector_type(2)));
typedef unsigned short us4 __attribute__((ext_vector_type(4)));

__device__ __forceinline__ unsigned short bf16rne(float f) {
    unsigned int u = __float_as_uint(f);
    return (unsigned short)((u + 0x7FFFu + ((u >> 16) & 1u)) >> 16);
}
__device__ __forceinline__ float bf2f(unsigned short b) {
    return __uint_as_float((unsigned int)b << 16);
}
// f32 -> fp8 e4m3 (OCP), HW convert (RNE+sat)
__device__ __forceinline__ unsigned char f32_to_fp8(float v) {
    int p = __builtin_amdgcn_cvt_pk_fp8_f32(v, v, 0, false);
    return (unsigned char)(p & 0xFF);
}

// async 16B global -> LDS (direct, no VGPR round-trip)
__device__ __forceinline__ void gl2lds16(const unsigned short* g, unsigned short* l) {
    __builtin_amdgcn_global_load_lds(
        (const __attribute__((address_space(1))) void*)g,
        (__attribute__((address_space(3))) void*)l, 16, 0, 0);
}

// ---------------- merged prologue: W->bf16 frag-major, bounds, sums, deg_count ----

__device__ __forceinline__ void wconv_one(const float* __restrict__ W,
                                          unsigned short* __restrict__ Bh, int i) {
    int k = i >> 8, c = i & 255;
    size_t pos = (size_t)(k >> 5) * 8192 + (size_t)(((c >> 4) * 4 + ((k >> 3) & 3)) * 128 + (c & 15) * 8 + (k & 7));
    Bh[pos] = bf16rne(W[i]);
}

__global__ __launch_bounds__(256)
void k_prep(const float* __restrict__ W1, unsigned short* __restrict__ Bh1,
            const float* __restrict__ W2, unsigned short* __restrict__ Bh2,
            const int* __restrict__ batch, int* __restrict__ bounds, float* __restrict__ sums,
            const int* __restrict__ dst, int* __restrict__ deg_i) {
    const int T = gridDim.x * 256;
    const int gid = blockIdx.x * 256 + threadIdx.x;
    for (int i = gid; i < IN_DIM * 256; i += T) wconv_one(W1, Bh1, i);
    for (int i = gid; i < HID_DIM * 256; i += T) wconv_one(W2, Bh2, i);
    for (int i = gid; i < N_GRAPHS * HID_DIM; i += T) sums[i] = 0.f;
    if (gid <= N_GRAPHS) {
        int lo = 0, hi = N_NODES;
        while (lo < hi) {
            int mid = (lo + hi) >> 1;
            if (batch[mid] < gid) lo = mid + 1; else hi = mid;
        }
        bounds[gid] = lo;
    }
    for (int e = gid; e < N_EDGES; e += T) atomicAdd(&deg_i[dst[e]], 1);
}

#define SCAN_BLK 1024
#define SCAN_NBLK ((N_NODES + SCAN_BLK - 1) / SCAN_BLK)  // 49

__global__ __launch_bounds__(SCAN_BLK)
void k_scan_blk(const int* __restrict__ deg, int* __restrict__ row_start,
                float* __restrict__ dinv, int* __restrict__ blk_tot) {
    __shared__ int tmp[SCAN_BLK];
    int t = threadIdx.x;
    int i = blockIdx.x * SCAN_BLK + t;
    int d = 0;
    if (i < N_NODES) {
        d = deg[i];
        dinv[i] = rsqrtf((float)d + 1.0f);
    }
    tmp[t] = d;
    __syncthreads();
    #pragma unroll
    for (int off = 1; off < SCAN_BLK; off <<= 1) {
        int v = (t >= off) ? tmp[t - off] : 0;
        __syncthreads();
        tmp[t] += v;
        __syncthreads();
    }
    if (i < N_NODES) row_start[i] = tmp[t] - d;
    if (t == SCAN_BLK - 1) blk_tot[blockIdx.x] = tmp[t];
}

// merged: scan offset fix (blocks < SCAN_NBLK) + xf8 build (grid-stride)
// xf8[n,c] = fp8(x[n,c] * dinv[n] * 8)
__global__ __launch_bounds__(SCAN_BLK)
void k_scan_fix(int* __restrict__ row_start, const int* __restrict__ blk_tot,
                const float* __restrict__ x, const float* __restrict__ dinv,
                unsigned char* __restrict__ xf8) {
    const int t = threadIdx.x, bid = blockIdx.x;
    if (bid < SCAN_NBLK) {
        __shared__ int soff;
        if (t < 64) {
            int v = (t < bid) ? blk_tot[t] : 0;
            #pragma unroll
            for (int m = 1; m < 64; m <<= 1) v += __shfl_xor(v, m, 64);
            if (t == 0) soff = v;
        }
        __syncthreads();
        int i = bid * SCAN_BLK + t;
        if (i < N_NODES) row_start[i] += soff;
        if (bid == 0 && t == 0) row_start[N_NODES] = N_EDGES;
    }
    const int T = gridDim.x * SCAN_BLK;
    for (int i = bid * SCAN_BLK + t; i < N_NODES * IN_DIM / 4; i += T) {
        float4 v = ((const float4*)x)[i];
        float s = dinv[i >> 5] * 8.f;
        unsigned int lo = (unsigned int)__builtin_amdgcn_cvt_pk_fp8_f32(v.x * s, v.y * s, 0, false) & 0xFFFFu;
        unsigned int hi = (unsigned int)__builtin_amdgcn_cvt_pk_fp8_f32(v.z * s, v.w * s, 0, false) & 0xFFFFu;
        ((unsigned int*)xf8)[i] = lo | (hi << 16);
    }
}

__global__ void k_csr_fill(const int* __restrict__ src, const int* __restrict__ dst,
                           const int* __restrict__ row_start, int* __restrict__ cursor,
                           int* __restrict__ col) {
    int e = blockIdx.x * blockDim.x + threadIdx.x;
    if (e < N_EDGES) {
        int d = dst[e];
        int pos = atomicAdd(&cursor[d], 1);
        col[row_start[d] + pos] = src[e];
    }
}

// ---------------- MFMA GEMM: [M,256] = epilogue(A[M,K] @ B[K,256]) --------
// K=128: whole-K LDS stage, ONE barrier. K=256: BK=64 double-buffered.
// B: bf16 fragment-major global image, read direct to registers (L2-resident).
// MODE 0: Cf8 = fp8(acc * dinv[m] * 16);  MODE 1: Cbf = bf16(relu(acc + bias[c]))

template<int MODE, int K>
__global__ __launch_bounds__(256)
void k_gemm_mfma(const unsigned short* __restrict__ Ah,
                 const unsigned short* __restrict__ Bh,
                 const float* __restrict__ dinv, const float* __restrict__ bias,
                 unsigned short* __restrict__ Cbf, unsigned char* __restrict__ Cf8,
                 int M) {
    __shared__ unsigned short AhL[4][2048];  // 16KB

    const int tid = threadIdx.x;
    const int wv = tid >> 6, lane = tid & 63;
    const int m0 = blockIdx.x * 64;

    const int ar = wv * 16 + (lane & 15);
    const int kseg = lane >> 4;
    const unsigned short* aph = Ah + (size_t)(m0 + ar) * K + kseg * 8;
    const int adoff = (wv * 64 + lane) * 8;

    f4 acc[4][4];
    #pragma unroll
    for (int mi = 0; mi < 4; ++mi)
        #pragma unroll
        for (int nj = 0; nj < 4; ++nj)
            acc[mi][nj] = f4{0.f, 0.f, 0.f, 0.f};

    if constexpr (K == 128) {
        #pragma unroll
        for (int c = 0; c < 4; ++c) gl2lds16(aph + c * 32, &AhL[c][adoff]);
        __syncthreads();
        #pragma unroll
        for (int kk = 0; kk < 4; ++kk) {
            const unsigned short* gb = Bh + (size_t)kk * 8192 + wv * 2048 + lane * 8;
            sh8 bfh[4];
            #pragma unroll
            for (int nj = 0; nj < 4; ++nj)
                bfh[nj] = *reinterpret_cast<const sh8*>(gb + nj * 512);
            sh8 afh[4];
            #pragma unroll
            for (int mi = 0; mi < 4; ++mi)
                afh[mi] = *reinterpret_cast<const sh8*>(&AhL[kk][mi * 512 + lane * 8]);
            #pragma unroll
            for (int mi = 0; mi < 4; ++mi)
                #pragma unroll
                for (int nj = 0; nj < 4; ++nj)
                    acc[mi][nj] = __builtin_amdgcn_mfma_f32_16x16x32_bf16(afh[mi], bfh[nj], acc[mi][nj], 0, 0, 0);
        }
    } else {
        const int nsteps = K >> 6;
        gl2lds16(aph, &AhL[0][adoff]);
        gl2lds16(aph + 32, &AhL[1][adoff]);
        int cur = 0;
        for (int s = 0; s < nsteps; ++s) {
            __syncthreads();
            if (s + 1 < nsteps) {
                gl2lds16(aph + (s + 1) * 64, &AhL[(cur ^ 1) * 2][adoff]);
                gl2lds16(aph + (s + 1) * 64 + 32, &AhL[(cur ^ 1) * 2 + 1][adoff]);
            }
            #pragma unroll
            for (int kk = 0; kk < 2; ++kk) {
                const int bstep = s * 2 + kk;
                const unsigned short* gb = Bh + (size_t)bstep * 8192 + wv * 2048 + lane * 8;
                sh8 bfh[4];
                #pragma unroll
                for (int nj = 0; nj < 4; ++nj)
                    bfh[nj] = *reinterpret_cast<const sh8*>(gb + nj * 512);
                sh8 afh[4];
                #pragma unroll
                for (int mi = 0; mi < 4; ++mi)
                    afh[mi] = *reinterpret_cast<const sh8*>(&AhL[cur * 2 + kk][mi * 512 + lane * 8]);
                #pragma unroll
                for (int mi = 0; mi < 4; ++mi)
                    #pragma unroll
                    for (int nj = 0; nj < 4; ++nj)
                        acc[mi][nj] = __builtin_amdgcn_mfma_f32_16x16x32_bf16(afh[mi], bfh[nj], acc[mi][nj], 0, 0, 0);
            }
            cur ^= 1;
        }
    }

    #pragma unroll
    for (int mi = 0; mi < 4; ++mi) {
        #pragma unroll
        for (int q = 0; q < 4; ++q) {
            int grow = m0 + mi * 16 + (lane >> 4) * 4 + q;
            if (grow < M) {
                float dm16 = (MODE == 0) ? dinv[grow] * 16.f : 0.f;
                #pragma unroll
                for (int nj = 0; nj < 4; ++nj) {
                    int gcol = wv * 64 + nj * 16 + (lane & 15);
                    float v = acc[mi][nj][q];
                    if (MODE == 0) {
                        Cf8[(size_t)grow * 256 + gcol] = f32_to_fp8(v * dm16);
                    } else {
                        Cbf[(size_t)grow * 256 + gcol] = bf16rne(fmaxf(v + bias[gcol], 0.f));
                    }
                }
            }
        }
    }
}

// ---------------- aggregation ----------------

// layer-1: z[n] = dinv[n] * ( dinv[n]*x[n] + (1/8) * sum xf8[s] )
// xf8 pre-scaled by dinv[src]*8. Half-wave dual-edge + 8x unroll (uint gathers).
__global__ __launch_bounds__(256)
void k_agg_x(const float* __restrict__ x, const unsigned char* __restrict__ xf8,
             const int* __restrict__ row_start, const int* __restrict__ col,
             const float* __restrict__ dinv, unsigned short* __restrict__ zh) {
    int wv = threadIdx.x >> 6, lane = threadIdx.x & 63;
    int half = lane >> 5, sub = lane & 31;
    int n = blockIdx.x * 4 + wv;

    float a0 = 0.f, a1 = 0.f, a2 = 0.f, a3 = 0.f;
    float dn = dinv[n];
    if (half == 0) {
        float4 xs = ((const float4*)x)[(size_t)n * 32 + sub];
        a0 = xs.x * dn * 8.f; a1 = xs.y * dn * 8.f;
        a2 = xs.z * dn * 8.f; a3 = xs.w * dn * 8.f;
    }
    const unsigned int* xw = (const unsigned int*)xf8;   // 4 fp8 per uint
    int e = row_start[n] + half;
    const int e1 = row_start[n + 1];
    for (; e + 14 < e1; e += 16) {
        int s0 = col[e], s1 = col[e + 2], s2 = col[e + 4], s3 = col[e + 6];
        int s4 = col[e + 8], s5 = col[e + 10], s6 = col[e + 12], s7 = col[e + 14];
        unsigned int w0 = xw[(size_t)s0 * 32 + sub], w1 = xw[(size_t)s1 * 32 + sub];
        unsigned int w2 = xw[(size_t)s2 * 32 + sub], w3 = xw[(size_t)s3 * 32 + sub];
        unsigned int w4 = xw[(size_t)s4 * 32 + sub], w5 = xw[(size_t)s5 * 32 + sub];
        unsigned int w6 = xw[(size_t)s6 * 32 + sub], w7 = xw[(size_t)s7 * 32 + sub];
        #pragma unroll
        for (int k = 0; k < 8; ++k) {
            unsigned int w = (k == 0) ? w0 : (k == 1) ? w1 : (k == 2) ? w2 : (k == 3) ? w3
                           : (k == 4) ? w4 : (k == 5) ? w5 : (k == 6) ? w6 : w7;
            f2 p0 = __builtin_amdgcn_cvt_pk_f32_fp8(w, false);
            f2 p1 = __builtin_amdgcn_cvt_pk_f32_fp8(w, true);
            a0 += p0.x; a1 += p0.y; a2 += p1.x; a3 += p1.y;
        }
    }
    for (; e + 6 < e1; e += 8) {
        int s0 = col[e], s1 = col[e + 2], s2 = col[e + 4], s3 = col[e + 6];
        unsigned int w0 = xw[(size_t)s0 * 32 + sub], w1 = xw[(size_t)s1 * 32 + sub];
        unsigned int w2 = xw[(size_t)s2 * 32 + sub], w3 = xw[(size_t)s3 * 32 + sub];
        #pragma unroll
        for (int k = 0; k < 4; ++k) {
            unsigned int w = (k == 0) ? w0 : (k == 1) ? w1 : (k == 2) ? w2 : w3;
            f2 p0 = __builtin_amdgcn_cvt_pk_f32_fp8(w, false);
            f2 p1 = __builtin_amdgcn_cvt_pk_f32_fp8(w, true);
            a0 += p0.x; a1 += p0.y; a2 += p1.x; a3 += p1.y;
        }
    }
    for (; e < e1; e += 2) {
        int s = col[e];
        unsigned int w = xw[(size_t)s * 32 + sub];
        f2 p0 = __builtin_amdgcn_cvt_pk_f32_fp8(w, false);
        f2 p1 = __builtin_amdgcn_cvt_pk_f32_fp8(w, true);
        a0 += p0.x; a1 += p0.y; a2 += p1.x; a3 += p1.y;
    }
    a0 += __shfl_xor(a0, 32, 64);
    a1 += __shfl_xor(a1, 32, 64);
    a2 += __shfl_xor(a2, 32, 64);
    a3 += __shfl_xor(a3, 32, 64);
    if (half == 0) {
        float s = dn * 0.125f;   // undo x8 pre-scale
        us4 oh;
        oh.x = bf16rne(a0 * s);
        oh.y = bf16rne(a1 * s);
        oh.z = bf16rne(a2 * s);
        oh.w = bf16rne(a3 * s);
        ((us4*)zh)[(size_t)n * 32 + sub] = oh;
    }
}

// layer-2 agg + relu + mean-pool fused; FINAL FC fused via last-block-wins.
// yb = fp8(y2*16), pre-scaled by dinv[src]. 8 nodes / 512-thread block.
__global__ __launch_bounds__(512)
void k_agg_pool(const unsigned char* __restrict__ yb, const int* __restrict__ row_start,
                const int* __restrict__ col, const float* __restrict__ dinv,
                const float* __restrict__ bias, const int* __restrict__ batch,
                float* __restrict__ sums, unsigned int* __restrict__ sync_cnt,
                const int* __restrict__ bounds, const float* __restrict__ Wfc,
                const float* __restrict__ bfc, float* __restrict__ out) {
    __shared__ float lsum[8][256];
    __shared__ bool doneS;
    const int tid = threadIdx.x;
    const int wv = tid >> 6, lane = tid & 63;
    const int half = lane >> 5, sub = lane & 31;
    const int base = blockIdx.x * 8;
    const int n = base + wv;

    const bool uni = (batch[base] == batch[base + 7]);

    const uint2* y8 = (const uint2*)yb;   // 8 fp8 per element
    float a[8] = {0.f, 0.f, 0.f, 0.f, 0.f, 0.f, 0.f, 0.f};
    if (half == 0) {
        uint2 w = y8[(size_t)n * 32 + sub];
        f2 p0 = __builtin_amdgcn_cvt_pk_f32_fp8(w.x, false);
        f2 p1 = __builtin_amdgcn_cvt_pk_f32_fp8(w.x, true);
        f2 p2 = __builtin_amdgcn_cvt_pk_f32_fp8(w.y, false);
        f2 p3 = __builtin_amdgcn_cvt_pk_f32_fp8(w.y, true);
        a[0] = p0.x; a[1] = p0.y; a[2] = p1.x; a[3] = p1.y;
        a[4] = p2.x; a[5] = p2.y; a[6] = p3.x; a[7] = p3.y;
    }
    int e = row_start[n] + half;
    const int e1 = row_start[n + 1];
    for (; e + 6 < e1; e += 8) {
        int s0 = col[e], s1 = col[e + 2], s2 = col[e + 4], s3 = col[e + 6];
        uint2 w0 = y8[(size_t)s0 * 32 + sub], w1 = y8[(size_t)s1 * 32 + sub];
        uint2 w2 = y8[(size_t)s2 * 32 + sub], w3 = y8[(size_t)s3 * 32 + sub];
        #pragma unroll
        for (int k = 0; k < 4; ++k) {
            uint2 w = (k == 0) ? w0 : (k == 1) ? w1 : (k == 2) ? w2 : w3;
            f2 p0 = __builtin_amdgcn_cvt_pk_f32_fp8(w.x, false);
            f2 p1 = __builtin_amdgcn_cvt_pk_f32_fp8(w.x, true);
            f2 p2 = __builtin_amdgcn_cvt_pk_f32_fp8(w.y, false);
            f2 p3 = __builtin_amdgcn_cvt_pk_f32_fp8(w.y, true);
            a[0] += p0.x; a[1] += p0.y; a[2] += p1.x; a[3] += p1.y;
            a[4] += p2.x; a[5] += p2.y; a[6] += p3.x; a[7] += p3.y;
        }
    }
    for (; e < e1; e += 2) {
        int s = col[e];
        uint2 w = y8[(size_t)s * 32 + sub];
        f2 p0 = __builtin_amdgcn_cvt_pk_f32_fp8(w.x, false);
        f2 p1 = __builtin_amdgcn_cvt_pk_f32_fp8(w.x, true);
        f2 p2 = __builtin_amdgcn_cvt_pk_f32_fp8(w.y, false);
        f2 p3 = __builtin_amdgcn_cvt_pk_f32_fp8(w.y, true);
        a[0] += p0.x; a[1] += p0.y; a[2] += p1.x; a[3] += p1.y;
        a[4] += p2.x; a[5] += p2.y; a[6] += p3.x; a[7] += p3.y;
    }
    #pragma unroll
    for (int j = 0; j < 8; ++j) a[j] += __shfl_xor(a[j], 32, 64);

    if (half == 0) {
        float dn = dinv[n] * 0.0625f;   // undo x16 fp8 pre-scale
        float4 b0 = ((const float4*)bias)[sub * 2];
        float4 b1 = ((const float4*)bias)[sub * 2 + 1];
        float4 o0, o1;
        o0.x = fmaxf(a[0] * dn + b0.x, 0.f);
        o0.y = fmaxf(a[1] * dn + b0.y, 0.f);
        o0.z = fmaxf(a[2] * dn + b0.z, 0.f);
        o0.w = fmaxf(a[3] * dn + b0.w, 0.f);
        o1.x = fmaxf(a[4] * dn + b1.x, 0.f);
        o1.y = fmaxf(a[5] * dn + b1.y, 0.f);
        o1.z = fmaxf(a[6] * dn + b1.z, 0.f);
        o1.w = fmaxf(a[7] * dn + b1.w, 0.f);
        if (uni) {
            ((float4*)&lsum[wv][sub * 8])[0] = o0;
            ((float4*)&lsum[wv][sub * 8])[1] = o1;
        } else {
            int g = batch[n];
            atomicAdd(&sums[g * 256 + sub * 8 + 0], o0.x);
            atomicAdd(&sums[g * 256 + sub * 8 + 1], o0.y);
            atomicAdd(&sums[g * 256 + sub * 8 + 2], o0.z);
            atomicAdd(&sums[g * 256 + sub * 8 + 3], o0.w);
            atomicAdd(&sums[g * 256 + sub * 8 + 4], o1.x);
            atomicAdd(&sums[g * 256 + sub * 8 + 5], o1.y);
            atomicAdd(&sums[g * 256 + sub * 8 + 6], o1.z);
            atomicAdd(&sums[g * 256 + sub * 8 + 7], o1.w);
        }
    }
    __syncthreads();
    if (uni && tid < 256) {
        float v = 0.f;
        #pragma unroll
        for (int w = 0; w < 8; ++w) v += lsum[w][tid];
        atomicAdd(&sums[batch[base] * 256 + tid], v);
    }

    // -------- last-block-wins fused FC --------
    __syncthreads();
    if (tid == 0) {
        __threadfence();
        unsigned int t = atomicAdd(sync_cnt, 1u);
        doneS = (t == (unsigned int)(gridDim.x - 1));
    }
    __syncthreads();
    if (doneS) {
        __threadfence();  // acquire: all blocks' sums visible
        int w = tid >> 6, ln = tid & 63;
        #pragma unroll
        for (int gi = 0; gi < 8; ++gi) {
            int g = w * 8 + gi;
            float cnt = (float)(bounds[g + 1] - bounds[g]);
            float v = 0.f;
            #pragma unroll
            for (int c = 0; c < 4; ++c) v += sums[g * 256 + ln + c * 64] * Wfc[ln + c * 64];
            #pragma unroll
            for (int m = 1; m < 64; m <<= 1) v += __shfl_xor(v, m, 64);
            if (ln == 0) out[g] = v / fmaxf(cnt, 1.f) + bfc[0];
        }
    }
}

// ---------------- launch ----------------

extern "C" void kernel_launch(void* const* d_in, const int* in_sizes, int n_in,
                              void* d_out, int out_size, void* d_ws, size_t ws_size,
                              hipStream_t stream) {
    const float* x    = (const float*)d_in[0];
    const int*   ei   = (const int*)d_in[1];
    const int*   batch= (const int*)d_in[2];
    const float* W1   = (const float*)d_in[3];
    const float* b1   = (const float*)d_in[4];
    const float* W2   = (const float*)d_in[5];
    const float* b2   = (const float*)d_in[6];
    const float* Wfc  = (const float*)d_in[7];
    const float* bfc  = (const float*)d_in[8];
    float* out = (float*)d_out;

    const int* src = ei;
    const int* dst = ei + N_EDGES;

    char* ws = (char*)d_ws;
    const size_t PLANE256 = (size_t)M_PAD * 256 * 2;
    size_t off = 0;
    unsigned short* h1h = (unsigned short*)(ws + off); off += PLANE256;
    char*           r1  = (char*)(ws + off); off += PLANE256;  // zh then y2f8
    unsigned char*  xf8 = (unsigned char*)(ws + off); off += (size_t)N_NODES * 128;
    int*   deg_i     = (int*)  (ws + off); off += 200704;
    int*   cursor    = (int*)  (ws + off); off += 200704;
    float* dinv      = (float*)(ws + off); off += 200704;
    int*   row_start = (int*)  (ws + off); off += 200704;
    int*   col       = (int*)  (ws + off); off += (size_t)N_EDGES * 4;
    unsigned short* Bh1 = (unsigned short*)(ws + off); off += 65536;
    unsigned short* Bh2 = (unsigned short*)(ws + off); off += 131072;
    float* sums      = (float*)(ws + off); off += 65536;
    int*   bounds    = (int*)  (ws + off); off += 512;
    int*   blk_tot   = (int*)  (ws + off); off += 512;
    (void)ws_size; (void)in_sizes; (void)n_in; (void)out_size;

    unsigned short* zh   = (unsigned short*)r1;  // [M_PAD,128] bf16, dead after GEMM1
    unsigned char*  y2f8 = (unsigned char*)r1;   // [M_PAD,256] fp8, written by GEMM2
    // sync counter lives in the spare tail of the cursor region (zeroed by memset)
    unsigned int* sync_cnt = (unsigned int*)(cursor + N_NODES);

    // 1. zero counters + merged prologue + scan + xf8 + CSR
    hipMemsetAsync(deg_i, 0, 2 * 200704, stream);  // deg_i + cursor (+sync_cnt)
    k_prep<<<2048, 256, 0, stream>>>(W1, Bh1, W2, Bh2, batch, bounds, sums, dst, deg_i);
    k_scan_blk<<<SCAN_NBLK, SCAN_BLK, 0, stream>>>(deg_i, row_start, dinv, blk_tot);
    k_scan_fix<<<256, SCAN_BLK, 0, stream>>>(row_start, blk_tot, x, dinv, xf8);
    k_csr_fill<<<(N_EDGES + 255) / 256, 256, 0, stream>>>(src, dst, row_start, cursor, col);

    const int gemm_grid = (N_NODES + 63) / 64;  // 782

    // 2. layer 1: zh = bf16(A_hat @ x) ; h1h = bf16(relu(z @ W1 + b1))
    k_agg_x<<<N_NODES / 4, 256, 0, stream>>>(x, xf8, row_start, col, dinv, zh);
    k_gemm_mfma<1, 128><<<gemm_grid, 256, 0, stream>>>(zh, Bh1, dinv, b1, h1h, nullptr, N_NODES);

    // 3. layer 2: y2f8 = fp8((h1 @ W2) * dinv * 16) ; fused agg+relu+pool+FC
    k_gemm_mfma<0, 256><<<gemm_grid, 256, 0, stream>>>(h1h, Bh2, dinv, b2, nullptr, y2f8, N_NODES);
    k_agg_pool<<<N_NODES / 8, 512, 0, stream>>>(y2f8, row_start, col, dinv, b2, batch,
                                                sums, sync_cnt, bounds, Wfc, bfc, out);
}

// Round 19
// 210.193 us; speedup vs baseline: 1.6932x; 1.6932x over previous
//
#include <hip/hip_runtime.h>
#include <hip/hip_bf16.h>

#define N_NODES 50000
#define N_EDGES 800000
#define N_GRAPHS 64
#define IN_DIM 128
#define HID_DIM 256
#define M_PAD 50048   // N_NODES padded to multiple of 64 for GEMM staging

typedef short sh8 __attribute__((ext_vector_type(8)));
typedef float f4 __attribute__((ext_vector_type(4)));
typedef float f2 __attribute__((ext_vector_type(2)));
typedef unsigned short us4 __attribute__((ext_vector_type(4)));

__device__ __forceinline__ unsigned short bf16rne(float f) {
    unsigned int u = __float_as_uint(f);
    return (unsigned short)((u + 0x7FFFu + ((u >> 16) & 1u)) >> 16);
}
__device__ __forceinline__ float bf2f(unsigned short b) {
    return __uint_as_float((unsigned int)b << 16);
}
// f32 -> fp8 e4m3 (OCP), HW convert (RNE+sat)
__device__ __forceinline__ unsigned char f32_to_fp8(float v) {
    int p = __builtin_amdgcn_cvt_pk_fp8_f32(v, v, 0, false);
    return (unsigned char)(p & 0xFF);
}

// async 16B global -> LDS (direct, no VGPR round-trip)
__device__ __forceinline__ void gl2lds16(const unsigned short* g, unsigned short* l) {
    __builtin_amdgcn_global_load_lds(
        (const __attribute__((address_space(1))) void*)g,
        (__attribute__((address_space(3))) void*)l, 16, 0, 0);
}

// ---------------- merged prologue: W->bf16 frag-major, bounds, sums, deg_count ----

__device__ __forceinline__ void wconv_one(const float* __restrict__ W,
                                          unsigned short* __restrict__ Bh, int i) {
    int k = i >> 8, c = i & 255;
    size_t pos = (size_t)(k >> 5) * 8192 + (size_t)(((c >> 4) * 4 + ((k >> 3) & 3)) * 128 + (c & 15) * 8 + (k & 7));
    Bh[pos] = bf16rne(W[i]);
}

__global__ __launch_bounds__(256)
void k_prep(const float* __restrict__ W1, unsigned short* __restrict__ Bh1,
            const float* __restrict__ W2, unsigned short* __restrict__ Bh2,
            const int* __restrict__ batch, int* __restrict__ bounds, float* __restrict__ sums,
            const int* __restrict__ dst, int* __restrict__ deg_i) {
    const int T = gridDim.x * 256;
    const int gid = blockIdx.x * 256 + threadIdx.x;
    for (int i = gid; i < IN_DIM * 256; i += T) wconv_one(W1, Bh1, i);
    for (int i = gid; i < HID_DIM * 256; i += T) wconv_one(W2, Bh2, i);
    for (int i = gid; i < N_GRAPHS * HID_DIM; i += T) sums[i] = 0.f;
    if (gid <= N_GRAPHS) {
        int lo = 0, hi = N_NODES;
        while (lo < hi) {
            int mid = (lo + hi) >> 1;
            if (batch[mid] < gid) lo = mid + 1; else hi = mid;
        }
        bounds[gid] = lo;
    }
    for (int e = gid; e < N_EDGES; e += T) atomicAdd(&deg_i[dst[e]], 1);
}

#define SCAN_BLK 1024
#define SCAN_NBLK ((N_NODES + SCAN_BLK - 1) / SCAN_BLK)  // 49

__global__ __launch_bounds__(SCAN_BLK)
void k_scan_blk(const int* __restrict__ deg, int* __restrict__ row_start,
                float* __restrict__ dinv, int* __restrict__ blk_tot) {
    __shared__ int tmp[SCAN_BLK];
    int t = threadIdx.x;
    int i = blockIdx.x * SCAN_BLK + t;
    int d = 0;
    if (i < N_NODES) {
        d = deg[i];
        dinv[i] = rsqrtf((float)d + 1.0f);
    }
    tmp[t] = d;
    __syncthreads();
    #pragma unroll
    for (int off = 1; off < SCAN_BLK; off <<= 1) {
        int v = (t >= off) ? tmp[t - off] : 0;
        __syncthreads();
        tmp[t] += v;
        __syncthreads();
    }
    if (i < N_NODES) row_start[i] = tmp[t] - d;
    if (t == SCAN_BLK - 1) blk_tot[blockIdx.x] = tmp[t];
}

// merged: scan offset fix (blocks < SCAN_NBLK) + xf8 build (grid-stride)
// xf8[n,c] = fp8(x[n,c] * dinv[n] * 8)
__global__ __launch_bounds__(SCAN_BLK)
void k_scan_fix(int* __restrict__ row_start, const int* __restrict__ blk_tot,
                const float* __restrict__ x, const float* __restrict__ dinv,
                unsigned char* __restrict__ xf8) {
    const int t = threadIdx.x, bid = blockIdx.x;
    if (bid < SCAN_NBLK) {
        __shared__ int soff;
        if (t < 64) {
            int v = (t < bid) ? blk_tot[t] : 0;
            #pragma unroll
            for (int m = 1; m < 64; m <<= 1) v += __shfl_xor(v, m, 64);
            if (t == 0) soff = v;
        }
        __syncthreads();
        int i = bid * SCAN_BLK + t;
        if (i < N_NODES) row_start[i] += soff;
        if (bid == 0 && t == 0) row_start[N_NODES] = N_EDGES;
    }
    const int T = gridDim.x * SCAN_BLK;
    for (int i = bid * SCAN_BLK + t; i < N_NODES * IN_DIM / 4; i += T) {
        float4 v = ((const float4*)x)[i];
        float s = dinv[i >> 5] * 8.f;
        unsigned int lo = (unsigned int)__builtin_amdgcn_cvt_pk_fp8_f32(v.x * s, v.y * s, 0, false) & 0xFFFFu;
        unsigned int hi = (unsigned int)__builtin_amdgcn_cvt_pk_fp8_f32(v.z * s, v.w * s, 0, false) & 0xFFFFu;
        ((unsigned int*)xf8)[i] = lo | (hi << 16);
    }
}

__global__ void k_csr_fill(const int* __restrict__ src, const int* __restrict__ dst,
                           const int* __restrict__ row_start, int* __restrict__ cursor,
                           int* __restrict__ col) {
    int e = blockIdx.x * blockDim.x + threadIdx.x;
    if (e < N_EDGES) {
        int d = dst[e];
        int pos = atomicAdd(&cursor[d], 1);
        col[row_start[d] + pos] = src[e];
    }
}

// ---------------- MFMA GEMM: [M,256] = epilogue(A[M,K] @ B[K,256]) --------
// K=128: whole-K LDS stage, ONE barrier. K=256: BK=64 double-buffered.
// B: bf16 fragment-major global image, read direct to registers (L2-resident).
// MODE 0: Cf8 = fp8(acc * dinv[m] * 16);  MODE 1: Cbf = bf16(relu(acc + bias[c]))

template<int MODE, int K>
__global__ __launch_bounds__(256)
void k_gemm_mfma(const unsigned short* __restrict__ Ah,
                 const unsigned short* __restrict__ Bh,
                 const float* __restrict__ dinv, const float* __restrict__ bias,
                 unsigned short* __restrict__ Cbf, unsigned char* __restrict__ Cf8,
                 int M) {
    __shared__ unsigned short AhL[4][2048];  // 16KB

    const int tid = threadIdx.x;
    const int wv = tid >> 6, lane = tid & 63;
    const int m0 = blockIdx.x * 64;

    const int ar = wv * 16 + (lane & 15);
    const int kseg = lane >> 4;
    const unsigned short* aph = Ah + (size_t)(m0 + ar) * K + kseg * 8;
    const int adoff = (wv * 64 + lane) * 8;

    f4 acc[4][4];
    #pragma unroll
    for (int mi = 0; mi < 4; ++mi)
        #pragma unroll
        for (int nj = 0; nj < 4; ++nj)
            acc[mi][nj] = f4{0.f, 0.f, 0.f, 0.f};

    if constexpr (K == 128) {
        #pragma unroll
        for (int c = 0; c < 4; ++c) gl2lds16(aph + c * 32, &AhL[c][adoff]);
        __syncthreads();
        #pragma unroll
        for (int kk = 0; kk < 4; ++kk) {
            const unsigned short* gb = Bh + (size_t)kk * 8192 + wv * 2048 + lane * 8;
            sh8 bfh[4];
            #pragma unroll
            for (int nj = 0; nj < 4; ++nj)
                bfh[nj] = *reinterpret_cast<const sh8*>(gb + nj * 512);
            sh8 afh[4];
            #pragma unroll
            for (int mi = 0; mi < 4; ++mi)
                afh[mi] = *reinterpret_cast<const sh8*>(&AhL[kk][mi * 512 + lane * 8]);
            #pragma unroll
            for (int mi = 0; mi < 4; ++mi)
                #pragma unroll
                for (int nj = 0; nj < 4; ++nj)
                    acc[mi][nj] = __builtin_amdgcn_mfma_f32_16x16x32_bf16(afh[mi], bfh[nj], acc[mi][nj], 0, 0, 0);
        }
    } else {
        const int nsteps = K >> 6;
        gl2lds16(aph, &AhL[0][adoff]);
        gl2lds16(aph + 32, &AhL[1][adoff]);
        int cur = 0;
        for (int s = 0; s < nsteps; ++s) {
            __syncthreads();
            if (s + 1 < nsteps) {
                gl2lds16(aph + (s + 1) * 64, &AhL[(cur ^ 1) * 2][adoff]);
                gl2lds16(aph + (s + 1) * 64 + 32, &AhL[(cur ^ 1) * 2 + 1][adoff]);
            }
            #pragma unroll
            for (int kk = 0; kk < 2; ++kk) {
                const int bstep = s * 2 + kk;
                const unsigned short* gb = Bh + (size_t)bstep * 8192 + wv * 2048 + lane * 8;
                sh8 bfh[4];
                #pragma unroll
                for (int nj = 0; nj < 4; ++nj)
                    bfh[nj] = *reinterpret_cast<const sh8*>(gb + nj * 512);
                sh8 afh[4];
                #pragma unroll
                for (int mi = 0; mi < 4; ++mi)
                    afh[mi] = *reinterpret_cast<const sh8*>(&AhL[cur * 2 + kk][mi * 512 + lane * 8]);
                #pragma unroll
                for (int mi = 0; mi < 4; ++mi)
                    #pragma unroll
                    for (int nj = 0; nj < 4; ++nj)
                        acc[mi][nj] = __builtin_amdgcn_mfma_f32_16x16x32_bf16(afh[mi], bfh[nj], acc[mi][nj], 0, 0, 0);
            }
            cur ^= 1;
        }
    }

    #pragma unroll
    for (int mi = 0; mi < 4; ++mi) {
        #pragma unroll
        for (int q = 0; q < 4; ++q) {
            int grow = m0 + mi * 16 + (lane >> 4) * 4 + q;
            if (grow < M) {
                float dm16 = (MODE == 0) ? dinv[grow] * 16.f : 0.f;
                #pragma unroll
                for (int nj = 0; nj < 4; ++nj) {
                    int gcol = wv * 64 + nj * 16 + (lane & 15);
                    float v = acc[mi][nj][q];
                    if (MODE == 0) {
                        Cf8[(size_t)grow * 256 + gcol] = f32_to_fp8(v * dm16);
                    } else {
                        Cbf[(size_t)grow * 256 + gcol] = bf16rne(fmaxf(v + bias[gcol], 0.f));
                    }
                }
            }
        }
    }
}

// ---------------- aggregation ----------------

// layer-1: z[n] = dinv[n] * ( dinv[n]*x[n] + (1/8) * sum xf8[s] )
// xf8 pre-scaled by dinv[src]*8. Half-wave dual-edge + 8x unroll (uint gathers).
__global__ __launch_bounds__(256)
void k_agg_x(const float* __restrict__ x, const unsigned char* __restrict__ xf8,
             const int* __restrict__ row_start, const int* __restrict__ col,
             const float* __restrict__ dinv, unsigned short* __restrict__ zh) {
    int wv = threadIdx.x >> 6, lane = threadIdx.x & 63;
    int half = lane >> 5, sub = lane & 31;
    int n = blockIdx.x * 4 + wv;

    float a0 = 0.f, a1 = 0.f, a2 = 0.f, a3 = 0.f;
    float dn = dinv[n];
    if (half == 0) {
        float4 xs = ((const float4*)x)[(size_t)n * 32 + sub];
        a0 = xs.x * dn * 8.f; a1 = xs.y * dn * 8.f;
        a2 = xs.z * dn * 8.f; a3 = xs.w * dn * 8.f;
    }
    const unsigned int* xw = (const unsigned int*)xf8;   // 4 fp8 per uint
    int e = row_start[n] + half;
    const int e1 = row_start[n + 1];
    for (; e + 14 < e1; e += 16) {
        int s0 = col[e], s1 = col[e + 2], s2 = col[e + 4], s3 = col[e + 6];
        int s4 = col[e + 8], s5 = col[e + 10], s6 = col[e + 12], s7 = col[e + 14];
        unsigned int w0 = xw[(size_t)s0 * 32 + sub], w1 = xw[(size_t)s1 * 32 + sub];
        unsigned int w2 = xw[(size_t)s2 * 32 + sub], w3 = xw[(size_t)s3 * 32 + sub];
        unsigned int w4 = xw[(size_t)s4 * 32 + sub], w5 = xw[(size_t)s5 * 32 + sub];
        unsigned int w6 = xw[(size_t)s6 * 32 + sub], w7 = xw[(size_t)s7 * 32 + sub];
        #pragma unroll
        for (int k = 0; k < 8; ++k) {
            unsigned int w = (k == 0) ? w0 : (k == 1) ? w1 : (k == 2) ? w2 : (k == 3) ? w3
                           : (k == 4) ? w4 : (k == 5) ? w5 : (k == 6) ? w6 : w7;
            f2 p0 = __builtin_amdgcn_cvt_pk_f32_fp8(w, false);
            f2 p1 = __builtin_amdgcn_cvt_pk_f32_fp8(w, true);
            a0 += p0.x; a1 += p0.y; a2 += p1.x; a3 += p1.y;
        }
    }
    for (; e + 6 < e1; e += 8) {
        int s0 = col[e], s1 = col[e + 2], s2 = col[e + 4], s3 = col[e + 6];
        unsigned int w0 = xw[(size_t)s0 * 32 + sub], w1 = xw[(size_t)s1 * 32 + sub];
        unsigned int w2 = xw[(size_t)s2 * 32 + sub], w3 = xw[(size_t)s3 * 32 + sub];
        #pragma unroll
        for (int k = 0; k < 4; ++k) {
            unsigned int w = (k == 0) ? w0 : (k == 1) ? w1 : (k == 2) ? w2 : w3;
            f2 p0 = __builtin_amdgcn_cvt_pk_f32_fp8(w, false);
            f2 p1 = __builtin_amdgcn_cvt_pk_f32_fp8(w, true);
            a0 += p0.x; a1 += p0.y; a2 += p1.x; a3 += p1.y;
        }
    }
    for (; e < e1; e += 2) {
        int s = col[e];
        unsigned int w = xw[(size_t)s * 32 + sub];
        f2 p0 = __builtin_amdgcn_cvt_pk_f32_fp8(w, false);
        f2 p1 = __builtin_amdgcn_cvt_pk_f32_fp8(w, true);
        a0 += p0.x; a1 += p0.y; a2 += p1.x; a3 += p1.y;
    }
    a0 += __shfl_xor(a0, 32, 64);
    a1 += __shfl_xor(a1, 32, 64);
    a2 += __shfl_xor(a2, 32, 64);
    a3 += __shfl_xor(a3, 32, 64);
    if (half == 0) {
        float s = dn * 0.125f;   // undo x8 pre-scale
        us4 oh;
        oh.x = bf16rne(a0 * s);
        oh.y = bf16rne(a1 * s);
        oh.z = bf16rne(a2 * s);
        oh.w = bf16rne(a3 * s);
        ((us4*)zh)[(size_t)n * 32 + sub] = oh;
    }
}

// layer-2 agg + relu + mean-pool fused. yb = fp8(y2*16), pre-scaled by dinv[src].
// 8 nodes per 512-thread block. Half-wave dual-edge + 4x unroll (uint2 gathers).
__global__ __launch_bounds__(512)
void k_agg_pool(const unsigned char* __restrict__ yb, const int* __restrict__ row_start,
                const int* __restrict__ col, const float* __restrict__ dinv,
                const float* __restrict__ bias, const int* __restrict__ batch,
                float* __restrict__ sums) {
    __shared__ float lsum[8][256];
    const int tid = threadIdx.x;
    const int wv = tid >> 6, lane = tid & 63;
    const int half = lane >> 5, sub = lane & 31;
    const int base = blockIdx.x * 8;
    const int n = base + wv;

    const bool uni = (batch[base] == batch[base + 7]);

    const uint2* y8 = (const uint2*)yb;   // 8 fp8 per element
    float a[8] = {0.f, 0.f, 0.f, 0.f, 0.f, 0.f, 0.f, 0.f};
    if (half == 0) {
        uint2 w = y8[(size_t)n * 32 + sub];
        f2 p0 = __builtin_amdgcn_cvt_pk_f32_fp8(w.x, false);
        f2 p1 = __builtin_amdgcn_cvt_pk_f32_fp8(w.x, true);
        f2 p2 = __builtin_amdgcn_cvt_pk_f32_fp8(w.y, false);
        f2 p3 = __builtin_amdgcn_cvt_pk_f32_fp8(w.y, true);
        a[0] = p0.x; a[1] = p0.y; a[2] = p1.x; a[3] = p1.y;
        a[4] = p2.x; a[5] = p2.y; a[6] = p3.x; a[7] = p3.y;
    }
    int e = row_start[n] + half;
    const int e1 = row_start[n + 1];
    for (; e + 6 < e1; e += 8) {
        int s0 = col[e], s1 = col[e + 2], s2 = col[e + 4], s3 = col[e + 6];
        uint2 w0 = y8[(size_t)s0 * 32 + sub], w1 = y8[(size_t)s1 * 32 + sub];
        uint2 w2 = y8[(size_t)s2 * 32 + sub], w3 = y8[(size_t)s3 * 32 + sub];
        #pragma unroll
        for (int k = 0; k < 4; ++k) {
            uint2 w = (k == 0) ? w0 : (k == 1) ? w1 : (k == 2) ? w2 : w3;
            f2 p0 = __builtin_amdgcn_cvt_pk_f32_fp8(w.x, false);
            f2 p1 = __builtin_amdgcn_cvt_pk_f32_fp8(w.x, true);
            f2 p2 = __builtin_amdgcn_cvt_pk_f32_fp8(w.y, false);
            f2 p3 = __builtin_amdgcn_cvt_pk_f32_fp8(w.y, true);
            a[0] += p0.x; a[1] += p0.y; a[2] += p1.x; a[3] += p1.y;
            a[4] += p2.x; a[5] += p2.y; a[6] += p3.x; a[7] += p3.y;
        }
    }
    for (; e < e1; e += 2) {
        int s = col[e];
        uint2 w = y8[(size_t)s * 32 + sub];
        f2 p0 = __builtin_amdgcn_cvt_pk_f32_fp8(w.x, false);
        f2 p1 = __builtin_amdgcn_cvt_pk_f32_fp8(w.x, true);
        f2 p2 = __builtin_amdgcn_cvt_pk_f32_fp8(w.y, false);
        f2 p3 = __builtin_amdgcn_cvt_pk_f32_fp8(w.y, true);
        a[0] += p0.x; a[1] += p0.y; a[2] += p1.x; a[3] += p1.y;
        a[4] += p2.x; a[5] += p2.y; a[6] += p3.x; a[7] += p3.y;
    }
    #pragma unroll
    for (int j = 0; j < 8; ++j) a[j] += __shfl_xor(a[j], 32, 64);

    if (half == 0) {
        float dn = dinv[n] * 0.0625f;   // undo x16 fp8 pre-scale
        float4 b0 = ((const float4*)bias)[sub * 2];
        float4 b1 = ((const float4*)bias)[sub * 2 + 1];
        float4 o0, o1;
        o0.x = fmaxf(a[0] * dn + b0.x, 0.f);
        o0.y = fmaxf(a[1] * dn + b0.y, 0.f);
        o0.z = fmaxf(a[2] * dn + b0.z, 0.f);
        o0.w = fmaxf(a[3] * dn + b0.w, 0.f);
        o1.x = fmaxf(a[4] * dn + b1.x, 0.f);
        o1.y = fmaxf(a[5] * dn + b1.y, 0.f);
        o1.z = fmaxf(a[6] * dn + b1.z, 0.f);
        o1.w = fmaxf(a[7] * dn + b1.w, 0.f);
        if (uni) {
            ((float4*)&lsum[wv][sub * 8])[0] = o0;
            ((float4*)&lsum[wv][sub * 8])[1] = o1;
        } else {
            int g = batch[n];
            atomicAdd(&sums[g * 256 + sub * 8 + 0], o0.x);
            atomicAdd(&sums[g * 256 + sub * 8 + 1], o0.y);
            atomicAdd(&sums[g * 256 + sub * 8 + 2], o0.z);
            atomicAdd(&sums[g * 256 + sub * 8 + 3], o0.w);
            atomicAdd(&sums[g * 256 + sub * 8 + 4], o1.x);
            atomicAdd(&sums[g * 256 + sub * 8 + 5], o1.y);
            atomicAdd(&sums[g * 256 + sub * 8 + 6], o1.z);
            atomicAdd(&sums[g * 256 + sub * 8 + 7], o1.w);
        }
    }
    __syncthreads();
    if (uni && tid < 256) {
        float v = 0.f;
        #pragma unroll
        for (int w = 0; w < 8; ++w) v += lsum[w][tid];
        atomicAdd(&sums[batch[base] * 256 + tid], v);
    }
}

// ---------------- FC ----------------

__global__ void k_final(const float* __restrict__ sums, const int* __restrict__ bounds,
                        const float* __restrict__ Wfc, const float* __restrict__ bfc,
                        float* __restrict__ out) {
    __shared__ float red[HID_DIM];
    int g = blockIdx.x;
    int c = threadIdx.x;
    float cnt = (float)(bounds[g + 1] - bounds[g]);
    float v = sums[g * HID_DIM + c] / fmaxf(cnt, 1.0f) * Wfc[c];
    red[c] = v;
    __syncthreads();
    for (int s = HID_DIM / 2; s > 0; s >>= 1) {
        if (c < s) red[c] += red[c + s];
        __syncthreads();
    }
    if (c == 0) out[g] = red[0] + bfc[0];
}

// ---------------- launch ----------------

extern "C" void kernel_launch(void* const* d_in, const int* in_sizes, int n_in,
                              void* d_out, int out_size, void* d_ws, size_t ws_size,
                              hipStream_t stream) {
    const float* x    = (const float*)d_in[0];
    const int*   ei   = (const int*)d_in[1];
    const int*   batch= (const int*)d_in[2];
    const float* W1   = (const float*)d_in[3];
    const float* b1   = (const float*)d_in[4];
    const float* W2   = (const float*)d_in[5];
    const float* b2   = (const float*)d_in[6];
    const float* Wfc  = (const float*)d_in[7];
    const float* bfc  = (const float*)d_in[8];
    float* out = (float*)d_out;

    const int* src = ei;
    const int* dst = ei + N_EDGES;

    char* ws = (char*)d_ws;
    const size_t PLANE256 = (size_t)M_PAD * 256 * 2;
    size_t off = 0;
    unsigned short* h1h = (unsigned short*)(ws + off); off += PLANE256;
    char*           r1  = (char*)(ws + off); off += PLANE256;  // zh then y2f8
    unsigned char*  xf8 = (unsigned char*)(ws + off); off += (size_t)N_NODES * 128;
    int*   deg_i     = (int*)  (ws + off); off += 200704;
    int*   cursor    = (int*)  (ws + off); off += 200704;
    float* dinv      = (float*)(ws + off); off += 200704;
    int*   row_start = (int*)  (ws + off); off += 200704;
    int*   col       = (int*)  (ws + off); off += (size_t)N_EDGES * 4;
    unsigned short* Bh1 = (unsigned short*)(ws + off); off += 65536;
    unsigned short* Bh2 = (unsigned short*)(ws + off); off += 131072;
    float* sums      = (float*)(ws + off); off += 65536;
    int*   bounds    = (int*)  (ws + off); off += 512;
    int*   blk_tot   = (int*)  (ws + off); off += 512;
    (void)ws_size; (void)in_sizes; (void)n_in; (void)out_size;

    unsigned short* zh   = (unsigned short*)r1;  // [M_PAD,128] bf16, dead after GEMM1
    unsigned char*  y2f8 = (unsigned char*)r1;   // [M_PAD,256] fp8, written by GEMM2

    // 1. zero counters + merged prologue + scan + xf8 + CSR
    hipMemsetAsync(deg_i, 0, 2 * 200704, stream);  // deg_i + cursor
    k_prep<<<2048, 256, 0, stream>>>(W1, Bh1, W2, Bh2, batch, bounds, sums, dst, deg_i);
    k_scan_blk<<<SCAN_NBLK, SCAN_BLK, 0, stream>>>(deg_i, row_start, dinv, blk_tot);
    k_scan_fix<<<256, SCAN_BLK, 0, stream>>>(row_start, blk_tot, x, dinv, xf8);
    k_csr_fill<<<(N_EDGES + 255) / 256, 256, 0, stream>>>(src, dst, row_start, cursor, col);

    const int gemm_grid = (N_NODES + 63) / 64;  // 782

    // 2. layer 1: zh = bf16(A_hat @ x) ; h1h = bf16(relu(z @ W1 + b1))
    k_agg_x<<<N_NODES / 4, 256, 0, stream>>>(x, xf8, row_start, col, dinv, zh);
    k_gemm_mfma<1, 128><<<gemm_grid, 256, 0, stream>>>(zh, Bh1, dinv, b1, h1h, nullptr, N_NODES);

    // 3. layer 2: y2f8 = fp8((h1 @ W2) * dinv * 16) ; fused agg+relu+pool
    k_gemm_mfma<0, 256><<<gemm_grid, 256, 0, stream>>>(h1h, Bh2, dinv, b2, nullptr, y2f8, N_NODES);
    k_agg_pool<<<N_NODES / 8, 512, 0, stream>>>(y2f8, row_start, col, dinv, b2, batch, sums);

    // 4. fc
    k_final<<<N_GRAPHS, HID_DIM, 0, stream>>>(sums, bounds, Wfc, bfc, out);
}

// Round 20
// 181.313 us; speedup vs baseline: 1.9629x; 1.1593x over previous
//
#include <hip/hip_runtime.h>
#include <hip/hip_bf16.h>

#define N_NODES 50000
#define N_EDGES 800000
#define N_GRAPHS 64
#define IN_DIM 128
#define HID_DIM 256
#define M_PAD 50048   // N_NODES padded to multiple of 64 for GEMM staging

typedef short sh8 __attribute__((ext_vector_type(8)));
typedef float f4 __attribute__((ext_vector_type(4)));
typedef float f2 __attribute__((ext_vector_type(2)));
typedef unsigned short us4 __attribute__((ext_vector_type(4)));

__device__ __forceinline__ unsigned short bf16rne(float f) {
    unsigned int u = __float_as_uint(f);
    return (unsigned short)((u + 0x7FFFu + ((u >> 16) & 1u)) >> 16);
}
__device__ __forceinline__ float bf2f(unsigned short b) {
    return __uint_as_float((unsigned int)b << 16);
}
// f32 -> fp8 e4m3 (OCP), HW convert (RNE+sat)
__device__ __forceinline__ unsigned char f32_to_fp8(float v) {
    int p = __builtin_amdgcn_cvt_pk_fp8_f32(v, v, 0, false);
    return (unsigned char)(p & 0xFF);
}

// async 16B global -> LDS (direct, no VGPR round-trip)
__device__ __forceinline__ void gl2lds16(const unsigned short* g, unsigned short* l) {
    __builtin_amdgcn_global_load_lds(
        (const __attribute__((address_space(1))) void*)g,
        (__attribute__((address_space(3))) void*)l, 16, 0, 0);
}

// ---------------- merged prologue ----------------
// W->bf16 frag-major, bounds, sums zero, AND CSR phase-1:
// pos = atomicAdd(cursor[dst]), tmp[e] = pos<<16 | src  (cursor becomes deg)

__device__ __forceinline__ void wconv_one(const float* __restrict__ W,
                                          unsigned short* __restrict__ Bh, int i) {
    int k = i >> 8, c = i & 255;
    size_t pos = (size_t)(k >> 5) * 8192 + (size_t)(((c >> 4) * 4 + ((k >> 3) & 3)) * 128 + (c & 15) * 8 + (k & 7));
    Bh[pos] = bf16rne(W[i]);
}

__global__ __launch_bounds__(256)
void k_prep(const float* __restrict__ W1, unsigned short* __restrict__ Bh1,
            const float* __restrict__ W2, unsigned short* __restrict__ Bh2,
            const int* __restrict__ batch, int* __restrict__ bounds, float* __restrict__ sums,
            const int* __restrict__ src, const int* __restrict__ dst,
            int* __restrict__ cursor, unsigned int* __restrict__ tmp) {
    const int T = gridDim.x * 256;
    const int gid = blockIdx.x * 256 + threadIdx.x;
    for (int i = gid; i < IN_DIM * 256; i += T) wconv_one(W1, Bh1, i);
    for (int i = gid; i < HID_DIM * 256; i += T) wconv_one(W2, Bh2, i);
    for (int i = gid; i < N_GRAPHS * HID_DIM; i += T) sums[i] = 0.f;
    if (gid <= N_GRAPHS) {
        int lo = 0, hi = N_NODES;
        while (lo < hi) {
            int mid = (lo + hi) >> 1;
            if (batch[mid] < gid) lo = mid + 1; else hi = mid;
        }
        bounds[gid] = lo;
    }
    for (int e = gid; e < N_EDGES; e += T) {
        int d = dst[e];
        int pos = atomicAdd(&cursor[d], 1);
        tmp[e] = ((unsigned int)pos << 16) | (unsigned int)src[e];
    }
}

#define SCAN_BLK 1024
#define SCAN_NBLK ((N_NODES + SCAN_BLK - 1) / SCAN_BLK)  // 49

__global__ __launch_bounds__(SCAN_BLK)
void k_scan_blk(const int* __restrict__ deg, int* __restrict__ row_start,
                float* __restrict__ dinv, int* __restrict__ blk_tot) {
    __shared__ int tmp[SCAN_BLK];
    int t = threadIdx.x;
    int i = blockIdx.x * SCAN_BLK + t;
    int d = 0;
    if (i < N_NODES) {
        d = deg[i];
        dinv[i] = rsqrtf((float)d + 1.0f);
    }
    tmp[t] = d;
    __syncthreads();
    #pragma unroll
    for (int off = 1; off < SCAN_BLK; off <<= 1) {
        int v = (t >= off) ? tmp[t - off] : 0;
        __syncthreads();
        tmp[t] += v;
        __syncthreads();
    }
    if (i < N_NODES) row_start[i] = tmp[t] - d;
    if (t == SCAN_BLK - 1) blk_tot[blockIdx.x] = tmp[t];
}

// merged: scan offset fix (blocks < SCAN_NBLK) + xf8 build (grid-stride)
// xf8[n,c] = fp8(x[n,c] * dinv[n] * 8)
__global__ __launch_bounds__(SCAN_BLK)
void k_scan_fix(int* __restrict__ row_start, const int* __restrict__ blk_tot,
                const float* __restrict__ x, const float* __restrict__ dinv,
                unsigned char* __restrict__ xf8) {
    const int t = threadIdx.x, bid = blockIdx.x;
    if (bid < SCAN_NBLK) {
        __shared__ int soff;
        if (t < 64) {
            int v = (t < bid) ? blk_tot[t] : 0;
            #pragma unroll
            for (int m = 1; m < 64; m <<= 1) v += __shfl_xor(v, m, 64);
            if (t == 0) soff = v;
        }
        __syncthreads();
        int i = bid * SCAN_BLK + t;
        if (i < N_NODES) row_start[i] += soff;
        if (bid == 0 && t == 0) row_start[N_NODES] = N_EDGES;
    }
    const int T = gridDim.x * SCAN_BLK;
    for (int i = bid * SCAN_BLK + t; i < N_NODES * IN_DIM / 4; i += T) {
        float4 v = ((const float4*)x)[i];
        float s = dinv[i >> 5] * 8.f;
        unsigned int lo = (unsigned int)__builtin_amdgcn_cvt_pk_fp8_f32(v.x * s, v.y * s, 0, false) & 0xFFFFu;
        unsigned int hi = (unsigned int)__builtin_amdgcn_cvt_pk_fp8_f32(v.z * s, v.w * s, 0, false) & 0xFFFFu;
        ((unsigned int*)xf8)[i] = lo | (hi << 16);
    }
}

// CSR phase-2: atomic-free scatter. col[row_start[dst]+pos] = src.
// 4 edges per thread, column-major (coalesced tmp/dst reads, 4 indep chains).
__global__ __launch_bounds__(256)
void k_csr_fill(const unsigned int* __restrict__ tmp, const int* __restrict__ dst,
                const int* __restrict__ row_start, int* __restrict__ col) {
    int base = blockIdx.x * 1024 + threadIdx.x;
    #pragma unroll
    for (int k = 0; k < 4; ++k) {
        int e = base + k * 256;
        if (e < N_EDGES) {
            unsigned int t = tmp[e];
            int d = dst[e];
            col[row_start[d] + (int)(t >> 16)] = (int)(t & 0xFFFFu);
        }
    }
}

// ---------------- MFMA GEMM: [M,256] = epilogue(A[M,K] @ B[K,256]) --------
// K=128: whole-K LDS stage, ONE barrier. K=256: BK=64 double-buffered.
// B: bf16 fragment-major global image, read direct to registers (L2-resident).
// MODE 0: Cf8 = fp8(acc * dinv[m] * 16);  MODE 1: Cbf = bf16(relu(acc + bias[c]))

template<int MODE, int K>
__global__ __launch_bounds__(256)
void k_gemm_mfma(const unsigned short* __restrict__ Ah,
                 const unsigned short* __restrict__ Bh,
                 const float* __restrict__ dinv, const float* __restrict__ bias,
                 unsigned short* __restrict__ Cbf, unsigned char* __restrict__ Cf8,
                 int M) {
    __shared__ unsigned short AhL[4][2048];  // 16KB

    const int tid = threadIdx.x;
    const int wv = tid >> 6, lane = tid & 63;
    const int m0 = blockIdx.x * 64;

    const int ar = wv * 16 + (lane & 15);
    const int kseg = lane >> 4;
    const unsigned short* aph = Ah + (size_t)(m0 + ar) * K + kseg * 8;
    const int adoff = (wv * 64 + lane) * 8;

    f4 acc[4][4];
    #pragma unroll
    for (int mi = 0; mi < 4; ++mi)
        #pragma unroll
        for (int nj = 0; nj < 4; ++nj)
            acc[mi][nj] = f4{0.f, 0.f, 0.f, 0.f};

    if constexpr (K == 128) {
        #pragma unroll
        for (int c = 0; c < 4; ++c) gl2lds16(aph + c * 32, &AhL[c][adoff]);
        __syncthreads();
        #pragma unroll
        for (int kk = 0; kk < 4; ++kk) {
            const unsigned short* gb = Bh + (size_t)kk * 8192 + wv * 2048 + lane * 8;
            sh8 bfh[4];
            #pragma unroll
            for (int nj = 0; nj < 4; ++nj)
                bfh[nj] = *reinterpret_cast<const sh8*>(gb + nj * 512);
            sh8 afh[4];
            #pragma unroll
            for (int mi = 0; mi < 4; ++mi)
                afh[mi] = *reinterpret_cast<const sh8*>(&AhL[kk][mi * 512 + lane * 8]);
            #pragma unroll
            for (int mi = 0; mi < 4; ++mi)
                #pragma unroll
                for (int nj = 0; nj < 4; ++nj)
                    acc[mi][nj] = __builtin_amdgcn_mfma_f32_16x16x32_bf16(afh[mi], bfh[nj], acc[mi][nj], 0, 0, 0);
        }
    } else {
        const int nsteps = K >> 6;
        gl2lds16(aph, &AhL[0][adoff]);
        gl2lds16(aph + 32, &AhL[1][adoff]);
        int cur = 0;
        for (int s = 0; s < nsteps; ++s) {
            __syncthreads();
            if (s + 1 < nsteps) {
                gl2lds16(aph + (s + 1) * 64, &AhL[(cur ^ 1) * 2][adoff]);
                gl2lds16(aph + (s + 1) * 64 + 32, &AhL[(cur ^ 1) * 2 + 1][adoff]);
            }
            #pragma unroll
            for (int kk = 0; kk < 2; ++kk) {
                const int bstep = s * 2 + kk;
                const unsigned short* gb = Bh + (size_t)bstep * 8192 + wv * 2048 + lane * 8;
                sh8 bfh[4];
                #pragma unroll
                for (int nj = 0; nj < 4; ++nj)
                    bfh[nj] = *reinterpret_cast<const sh8*>(gb + nj * 512);
                sh8 afh[4];
                #pragma unroll
                for (int mi = 0; mi < 4; ++mi)
                    afh[mi] = *reinterpret_cast<const sh8*>(&AhL[cur * 2 + kk][mi * 512 + lane * 8]);
                #pragma unroll
                for (int mi = 0; mi < 4; ++mi)
                    #pragma unroll
                    for (int nj = 0; nj < 4; ++nj)
                        acc[mi][nj] = __builtin_amdgcn_mfma_f32_16x16x32_bf16(afh[mi], bfh[nj], acc[mi][nj], 0, 0, 0);
            }
            cur ^= 1;
        }
    }

    #pragma unroll
    for (int mi = 0; mi < 4; ++mi) {
        #pragma unroll
        for (int q = 0; q < 4; ++q) {
            int grow = m0 + mi * 16 + (lane >> 4) * 4 + q;
            if (grow < M) {
                float dm16 = (MODE == 0) ? dinv[grow] * 16.f : 0.f;
                #pragma unroll
                for (int nj = 0; nj < 4; ++nj) {
                    int gcol = wv * 64 + nj * 16 + (lane & 15);
                    float v = acc[mi][nj][q];
                    if (MODE == 0) {
                        Cf8[(size_t)grow * 256 + gcol] = f32_to_fp8(v * dm16);
                    } else {
                        Cbf[(size_t)grow * 256 + gcol] = bf16rne(fmaxf(v + bias[gcol], 0.f));
                    }
                }
            }
        }
    }
}

// ---------------- aggregation ----------------

// layer-1: z[n] = dinv[n] * ( dinv[n]*x[n] + (1/8) * sum xf8[s] )
// xf8 pre-scaled by dinv[src]*8. Half-wave dual-edge + 8x unroll (uint gathers).
__global__ __launch_bounds__(256)
void k_agg_x(const float* __restrict__ x, const unsigned char* __restrict__ xf8,
             const int* __restrict__ row_start, const int* __restrict__ col,
             const float* __restrict__ dinv, unsigned short* __restrict__ zh) {
    int wv = threadIdx.x >> 6, lane = threadIdx.x & 63;
    int half = lane >> 5, sub = lane & 31;
    int n = blockIdx.x * 4 + wv;

    float a0 = 0.f, a1 = 0.f, a2 = 0.f, a3 = 0.f;
    float dn = dinv[n];
    if (half == 0) {
        float4 xs = ((const float4*)x)[(size_t)n * 32 + sub];
        a0 = xs.x * dn * 8.f; a1 = xs.y * dn * 8.f;
        a2 = xs.z * dn * 8.f; a3 = xs.w * dn * 8.f;
    }
    const unsigned int* xw = (const unsigned int*)xf8;   // 4 fp8 per uint
    int e = row_start[n] + half;
    const int e1 = row_start[n + 1];
    for (; e + 14 < e1; e += 16) {
        int s0 = col[e], s1 = col[e + 2], s2 = col[e + 4], s3 = col[e + 6];
        int s4 = col[e + 8], s5 = col[e + 10], s6 = col[e + 12], s7 = col[e + 14];
        unsigned int w0 = xw[(size_t)s0 * 32 + sub], w1 = xw[(size_t)s1 * 32 + sub];
        unsigned int w2 = xw[(size_t)s2 * 32 + sub], w3 = xw[(size_t)s3 * 32 + sub];
        unsigned int w4 = xw[(size_t)s4 * 32 + sub], w5 = xw[(size_t)s5 * 32 + sub];
        unsigned int w6 = xw[(size_t)s6 * 32 + sub], w7 = xw[(size_t)s7 * 32 + sub];
        #pragma unroll
        for (int k = 0; k < 8; ++k) {
            unsigned int w = (k == 0) ? w0 : (k == 1) ? w1 : (k == 2) ? w2 : (k == 3) ? w3
                           : (k == 4) ? w4 : (k == 5) ? w5 : (k == 6) ? w6 : w7;
            f2 p0 = __builtin_amdgcn_cvt_pk_f32_fp8(w, false);
            f2 p1 = __builtin_amdgcn_cvt_pk_f32_fp8(w, true);
            a0 += p0.x; a1 += p0.y; a2 += p1.x; a3 += p1.y;
        }
    }
    for (; e + 6 < e1; e += 8) {
        int s0 = col[e], s1 = col[e + 2], s2 = col[e + 4], s3 = col[e + 6];
        unsigned int w0 = xw[(size_t)s0 * 32 + sub], w1 = xw[(size_t)s1 * 32 + sub];
        unsigned int w2 = xw[(size_t)s2 * 32 + sub], w3 = xw[(size_t)s3 * 32 + sub];
        #pragma unroll
        for (int k = 0; k < 4; ++k) {
            unsigned int w = (k == 0) ? w0 : (k == 1) ? w1 : (k == 2) ? w2 : w3;
            f2 p0 = __builtin_amdgcn_cvt_pk_f32_fp8(w, false);
            f2 p1 = __builtin_amdgcn_cvt_pk_f32_fp8(w, true);
            a0 += p0.x; a1 += p0.y; a2 += p1.x; a3 += p1.y;
        }
    }
    for (; e < e1; e += 2) {
        int s = col[e];
        unsigned int w = xw[(size_t)s * 32 + sub];
        f2 p0 = __builtin_amdgcn_cvt_pk_f32_fp8(w, false);
        f2 p1 = __builtin_amdgcn_cvt_pk_f32_fp8(w, true);
        a0 += p0.x; a1 += p0.y; a2 += p1.x; a3 += p1.y;
    }
    a0 += __shfl_xor(a0, 32, 64);
    a1 += __shfl_xor(a1, 32, 64);
    a2 += __shfl_xor(a2, 32, 64);
    a3 += __shfl_xor(a3, 32, 64);
    if (half == 0) {
        float s = dn * 0.125f;   // undo x8 pre-scale
        us4 oh;
        oh.x = bf16rne(a0 * s);
        oh.y = bf16rne(a1 * s);
        oh.z = bf16rne(a2 * s);
        oh.w = bf16rne(a3 * s);
        ((us4*)zh)[(size_t)n * 32 + sub] = oh;
    }
}

// layer-2 agg + relu + mean-pool fused. yb = fp8(y2*16), pre-scaled by dinv[src].
// 8 nodes per 512-thread block. Half-wave dual-edge + 4x unroll (uint2 gathers).
__global__ __launch_bounds__(512)
void k_agg_pool(const unsigned char* __restrict__ yb, const int* __restrict__ row_start,
                const int* __restrict__ col, const float* __restrict__ dinv,
                const float* __restrict__ bias, const int* __restrict__ batch,
                float* __restrict__ sums) {
    __shared__ float lsum[8][256];
    const int tid = threadIdx.x;
    const int wv = tid >> 6, lane = tid & 63;
    const int half = lane >> 5, sub = lane & 31;
    const int base = blockIdx.x * 8;
    const int n = base + wv;

    const bool uni = (batch[base] == batch[base + 7]);

    const uint2* y8 = (const uint2*)yb;   // 8 fp8 per element
    float a[8] = {0.f, 0.f, 0.f, 0.f, 0.f, 0.f, 0.f, 0.f};
    if (half == 0) {
        uint2 w = y8[(size_t)n * 32 + sub];
        f2 p0 = __builtin_amdgcn_cvt_pk_f32_fp8(w.x, false);
        f2 p1 = __builtin_amdgcn_cvt_pk_f32_fp8(w.x, true);
        f2 p2 = __builtin_amdgcn_cvt_pk_f32_fp8(w.y, false);
        f2 p3 = __builtin_amdgcn_cvt_pk_f32_fp8(w.y, true);
        a[0] = p0.x; a[1] = p0.y; a[2] = p1.x; a[3] = p1.y;
        a[4] = p2.x; a[5] = p2.y; a[6] = p3.x; a[7] = p3.y;
    }
    int e = row_start[n] + half;
    const int e1 = row_start[n + 1];
    for (; e + 6 < e1; e += 8) {
        int s0 = col[e], s1 = col[e + 2], s2 = col[e + 4], s3 = col[e + 6];
        uint2 w0 = y8[(size_t)s0 * 32 + sub], w1 = y8[(size_t)s1 * 32 + sub];
        uint2 w2 = y8[(size_t)s2 * 32 + sub], w3 = y8[(size_t)s3 * 32 + sub];
        #pragma unroll
        for (int k = 0; k < 4; ++k) {
            uint2 w = (k == 0) ? w0 : (k == 1) ? w1 : (k == 2) ? w2 : w3;
            f2 p0 = __builtin_amdgcn_cvt_pk_f32_fp8(w.x, false);
            f2 p1 = __builtin_amdgcn_cvt_pk_f32_fp8(w.x, true);
            f2 p2 = __builtin_amdgcn_cvt_pk_f32_fp8(w.y, false);
            f2 p3 = __builtin_amdgcn_cvt_pk_f32_fp8(w.y, true);
            a[0] += p0.x; a[1] += p0.y; a[2] += p1.x; a[3] += p1.y;
            a[4] += p2.x; a[5] += p2.y; a[6] += p3.x; a[7] += p3.y;
        }
    }
    for (; e < e1; e += 2) {
        int s = col[e];
        uint2 w = y8[(size_t)s * 32 + sub];
        f2 p0 = __builtin_amdgcn_cvt_pk_f32_fp8(w.x, false);
        f2 p1 = __builtin_amdgcn_cvt_pk_f32_fp8(w.x, true);
        f2 p2 = __builtin_amdgcn_cvt_pk_f32_fp8(w.y, false);
        f2 p3 = __builtin_amdgcn_cvt_pk_f32_fp8(w.y, true);
        a[0] += p0.x; a[1] += p0.y; a[2] += p1.x; a[3] += p1.y;
        a[4] += p2.x; a[5] += p2.y; a[6] += p3.x; a[7] += p3.y;
    }
    #pragma unroll
    for (int j = 0; j < 8; ++j) a[j] += __shfl_xor(a[j], 32, 64);

    if (half == 0) {
        float dn = dinv[n] * 0.0625f;   // undo x16 fp8 pre-scale
        float4 b0 = ((const float4*)bias)[sub * 2];
        float4 b1 = ((const float4*)bias)[sub * 2 + 1];
        float4 o0, o1;
        o0.x = fmaxf(a[0] * dn + b0.x, 0.f);
        o0.y = fmaxf(a[1] * dn + b0.y, 0.f);
        o0.z = fmaxf(a[2] * dn + b0.z, 0.f);
        o0.w = fmaxf(a[3] * dn + b0.w, 0.f);
        o1.x = fmaxf(a[4] * dn + b1.x, 0.f);
        o1.y = fmaxf(a[5] * dn + b1.y, 0.f);
        o1.z = fmaxf(a[6] * dn + b1.z, 0.f);
        o1.w = fmaxf(a[7] * dn + b1.w, 0.f);
        if (uni) {
            ((float4*)&lsum[wv][sub * 8])[0] = o0;
            ((float4*)&lsum[wv][sub * 8])[1] = o1;
        } else {
            int g = batch[n];
            atomicAdd(&sums[g * 256 + sub * 8 + 0], o0.x);
            atomicAdd(&sums[g * 256 + sub * 8 + 1], o0.y);
            atomicAdd(&sums[g * 256 + sub * 8 + 2], o0.z);
            atomicAdd(&sums[g * 256 + sub * 8 + 3], o0.w);
            atomicAdd(&sums[g * 256 + sub * 8 + 4], o1.x);
            atomicAdd(&sums[g * 256 + sub * 8 + 5], o1.y);
            atomicAdd(&sums[g * 256 + sub * 8 + 6], o1.z);
            atomicAdd(&sums[g * 256 + sub * 8 + 7], o1.w);
        }
    }
    __syncthreads();
    if (uni && tid < 256) {
        float v = 0.f;
        #pragma unroll
        for (int w = 0; w < 8; ++w) v += lsum[w][tid];
        atomicAdd(&sums[batch[base] * 256 + tid], v);
    }
}

// ---------------- FC ----------------

__global__ void k_final(const float* __restrict__ sums, const int* __restrict__ bounds,
                        const float* __restrict__ Wfc, const float* __restrict__ bfc,
                        float* __restrict__ out) {
    __shared__ float red[HID_DIM];
    int g = blockIdx.x;
    int c = threadIdx.x;
    float cnt = (float)(bounds[g + 1] - bounds[g]);
    float v = sums[g * HID_DIM + c] / fmaxf(cnt, 1.0f) * Wfc[c];
    red[c] = v;
    __syncthreads();
    for (int s = HID_DIM / 2; s > 0; s >>= 1) {
        if (c < s) red[c] += red[c + s];
        __syncthreads();
    }
    if (c == 0) out[g] = red[0] + bfc[0];
}

// ---------------- launch ----------------

extern "C" void kernel_launch(void* const* d_in, const int* in_sizes, int n_in,
                              void* d_out, int out_size, void* d_ws, size_t ws_size,
                              hipStream_t stream) {
    const float* x    = (const float*)d_in[0];
    const int*   ei   = (const int*)d_in[1];
    const int*   batch= (const int*)d_in[2];
    const float* W1   = (const float*)d_in[3];
    const float* b1   = (const float*)d_in[4];
    const float* W2   = (const float*)d_in[5];
    const float* b2   = (const float*)d_in[6];
    const float* Wfc  = (const float*)d_in[7];
    const float* bfc  = (const float*)d_in[8];
    float* out = (float*)d_out;

    const int* src = ei;
    const int* dst = ei + N_EDGES;

    char* ws = (char*)d_ws;
    const size_t PLANE256 = (size_t)M_PAD * 256 * 2;
    size_t off = 0;
    unsigned short* h1h = (unsigned short*)(ws + off); off += PLANE256;
    char*           r1  = (char*)(ws + off); off += PLANE256;  // zh then y2f8
    unsigned char*  xf8 = (unsigned char*)(ws + off); off += (size_t)N_NODES * 128;
    int*   cursor    = (int*)  (ws + off); off += 200704;
    float* dinv      = (float*)(ws + off); off += 200704;
    int*   row_start = (int*)  (ws + off); off += 200704;
    int*   col       = (int*)  (ws + off); off += (size_t)N_EDGES * 4;
    unsigned int* tmp= (unsigned int*)(ws + off); off += (size_t)N_EDGES * 4;
    unsigned short* Bh1 = (unsigned short*)(ws + off); off += 65536;
    unsigned short* Bh2 = (unsigned short*)(ws + off); off += 131072;
    float* sums      = (float*)(ws + off); off += 65536;
    int*   bounds    = (int*)  (ws + off); off += 512;
    int*   blk_tot   = (int*)  (ws + off); off += 512;
    (void)ws_size; (void)in_sizes; (void)n_in; (void)out_size;

    unsigned short* zh   = (unsigned short*)r1;  // [M_PAD,128] bf16, dead after GEMM1
    unsigned char*  y2f8 = (unsigned char*)r1;   // [M_PAD,256] fp8, written by GEMM2

    // 1. zero cursor + merged prologue (CSR phase-1) + scan + xf8 + scatter fill
    hipMemsetAsync(cursor, 0, 200704, stream);
    k_prep<<<2048, 256, 0, stream>>>(W1, Bh1, W2, Bh2, batch, bounds, sums, src, dst, cursor, tmp);
    k_scan_blk<<<SCAN_NBLK, SCAN_BLK, 0, stream>>>(cursor, row_start, dinv, blk_tot);
    k_scan_fix<<<256, SCAN_BLK, 0, stream>>>(row_start, blk_tot, x, dinv, xf8);
    k_csr_fill<<<(N_EDGES + 1023) / 1024, 256, 0, stream>>>(tmp, dst, row_start, col);

    const int gemm_grid = (N_NODES + 63) / 64;  // 782

    // 2. layer 1: zh = bf16(A_hat @ x) ; h1h = bf16(relu(z @ W1 + b1))
    k_agg_x<<<N_NODES / 4, 256, 0, stream>>>(x, xf8, row_start, col, dinv, zh);
    k_gemm_mfma<1, 128><<<gemm_grid, 256, 0, stream>>>(zh, Bh1, dinv, b1, h1h, nullptr, N_NODES);

    // 3. layer 2: y2f8 = fp8((h1 @ W2) * dinv * 16) ; fused agg+relu+pool
    k_gemm_mfma<0, 256><<<gemm_grid, 256, 0, stream>>>(h1h, Bh2, dinv, b2, nullptr, y2f8, N_NODES);
    k_agg_pool<<<N_NODES / 8, 512, 0, stream>>>(y2f8, row_start, col, dinv, b2, batch, sums);

    // 4. fc
    k_final<<<N_GRAPHS, HID_DIM, 0, stream>>>(sums, bounds, Wfc, bfc, out);
}